// Round 1
// baseline (876.512 us; speedup 1.0000x reference)
//
#include <hip/hip_runtime.h>
#include <hip/hip_bf16.h>
#include <cstddef>

#define LN_EPS 1e-5f

// Problem dims (fixed by the reference)
#define B_DIM 8192
#define D_DIM 4096
#define H_DIM 2048
#define K_DIM 512

typedef __bf16 bf16x8_t __attribute__((ext_vector_type(8)));
typedef float f32x4_t __attribute__((ext_vector_type(4)));

// ---------------------------------------------------------------------------
// Stage a 128x32 tile of a row-major [rows x lda] matrix (K-contiguous) into
// LDS as bf16 with row stride 40 (pad 8 -> 80B rows, 2-way bank alias = free).
// 256 threads, 4 groups of 4 elems each (f32 path: float4 load + cvt).
// ---------------------------------------------------------------------------
template <typename T, bool SUBMEAN>
__device__ __forceinline__ void stage_tile(const T* __restrict__ src, int lda,
                                           long rowBase, int k0,
                                           const float* __restrict__ cmean,
                                           __hip_bfloat16* lds, int t) {
#pragma unroll
  for (int i = 0; i < 4; ++i) {
    int g = t + i * 256;      // 0..1023
    int row = g >> 3;         // 0..127
    int c4 = g & 7;           // 0..7
    int col = k0 + c4 * 4;
    const T* p = src + (rowBase + row) * (long)lda + col;
    if constexpr (sizeof(T) == 4) {
      float4 v = *(const float4*)p;
      if constexpr (SUBMEAN) {
        float4 m = *(const float4*)(cmean + col);
        v.x -= m.x; v.y -= m.y; v.z -= m.z; v.w -= m.w;
      }
      union { __hip_bfloat16 h[4]; uint2 u; } pk;
      pk.h[0] = __float2bfloat16(v.x);
      pk.h[1] = __float2bfloat16(v.y);
      pk.h[2] = __float2bfloat16(v.z);
      pk.h[3] = __float2bfloat16(v.w);
      *(uint2*)&lds[row * 40 + c4 * 4] = pk.u;
    } else {
      // already bf16 in global: straight 8B copy
      *(uint2*)&lds[row * 40 + c4 * 4] = *(const uint2*)p;
    }
  }
}

// ---------------------------------------------------------------------------
// C = A * B^T (+bias / epilogue), A: [M x Kd] row-major, Bm: [N x Kd] row-major
// (both K-contiguous -> NT GEMM). 128x128 tile, BK=32, 4 waves in 2x2, each
// wave does a 64x64 sub-tile as 4x4 mfma_f32_16x16x32_bf16.
// EPI 0: +bias, store f32 C0          (fc1 -> h)
// EPI 1: +bias, store f32 C0,C2,C3    (fc2 -> q_logits, 3 output copies)
// EPI 2: sigmoid, store f32 C0        (decode -> x_recon)
// ---------------------------------------------------------------------------
template <int EPI, typename TA, typename TB>
__global__ __launch_bounds__(256, 2) void gemm_nt(
    const TA* __restrict__ A, int lda, const TB* __restrict__ Bm, int ldb,
    const float* __restrict__ bias, const float* __restrict__ cmean,
    float* __restrict__ C0, int ldc, float* __restrict__ C2,
    float* __restrict__ C3, int Kd) {
  __shared__ __hip_bfloat16 lA[128 * 40];
  __shared__ __hip_bfloat16 lB[128 * 40];

  const int t = threadIdx.x;
  const int lane = t & 63;
  const int wv = t >> 6;
  const int wm = (wv >> 1) * 64;   // wave row offset in tile
  const int wn = (wv & 1) * 64;    // wave col offset in tile
  const int fr = lane & 15;        // A-row / B-col within 16, D-col
  const int ko = lane >> 4;        // k-quad

  const long rowBaseA = (long)blockIdx.y * 128;
  const long rowBaseB = (long)blockIdx.x * 128;

  f32x4_t acc[4][4];
  f32x4_t zero = {0.f, 0.f, 0.f, 0.f};
#pragma unroll
  for (int mi = 0; mi < 4; ++mi)
#pragma unroll
    for (int ni = 0; ni < 4; ++ni) acc[mi][ni] = zero;

  for (int k0 = 0; k0 < Kd; k0 += 32) {
    stage_tile<TA, (EPI == 0)>(A, lda, rowBaseA, k0, cmean, lA, t);
    stage_tile<TB, false>(Bm, ldb, rowBaseB, k0, nullptr, lB, t);
    __syncthreads();

    bf16x8_t af[4], bfv[4];
#pragma unroll
    for (int mi = 0; mi < 4; ++mi)
      af[mi] = *(const bf16x8_t*)&lA[(wm + mi * 16 + fr) * 40 + ko * 8];
#pragma unroll
    for (int ni = 0; ni < 4; ++ni)
      bfv[ni] = *(const bf16x8_t*)&lB[(wn + ni * 16 + fr) * 40 + ko * 8];
#pragma unroll
    for (int mi = 0; mi < 4; ++mi)
#pragma unroll
      for (int ni = 0; ni < 4; ++ni)
        acc[mi][ni] = __builtin_amdgcn_mfma_f32_16x16x32_bf16(
            af[mi], bfv[ni], acc[mi][ni], 0, 0, 0);
    __syncthreads();
  }

  // Epilogue. C/D layout (verified m89/m91): col = lane&15, row = (lane>>4)*4 + reg
  const long cRow0 = rowBaseA + wm;
  const int cCol0 = (int)rowBaseB + wn;
#pragma unroll
  for (int mi = 0; mi < 4; ++mi) {
#pragma unroll
    for (int ni = 0; ni < 4; ++ni) {
      f32x4_t a = acc[mi][ni];
      int col = cCol0 + ni * 16 + fr;
#pragma unroll
      for (int r = 0; r < 4; ++r) {
        long row = cRow0 + mi * 16 + ko * 4 + r;
        float val = a[r];
        if constexpr (EPI == 0) {
          val += bias[col];
          C0[row * (long)ldc + col] = val;
        } else if constexpr (EPI == 1) {
          val += bias[col];
          C0[row * (long)ldc + col] = val;
          C2[row * (long)ldc + col] = val;
          C3[row * (long)ldc + col] = val;
        } else {
          val = 1.f / (1.f + __expf(-val));
          C0[row * (long)ldc + col] = val;
        }
      }
    }
  }
}

// ---------------------------------------------------------------------------
// Row LayerNorm + ReLU over h [8192 x 2048] f32; writes bf16 h' IN PLACE over
// the same ws buffer (bf16 row stride 4096 elems = 8192 B = the f32 row size,
// so row i's bf16 data occupies the first half of row i's f32 bytes).
// Safe: all reads happen before the first __syncthreads, writes after.
// ---------------------------------------------------------------------------
__global__ __launch_bounds__(256) void ln_relu_kernel(
    void* hptr, const float* __restrict__ ln_w, const float* __restrict__ ln_b) {
  const int H = H_DIM;
  float* h = (float*)hptr;
  __hip_bfloat16* hb = (__hip_bfloat16*)hptr;

  const long row = blockIdx.x;
  const int t = threadIdx.x;
  const int lane = t & 63;
  const int wv = t >> 6;
  const float* hr = h + row * H;

  float v[8];
#pragma unroll
  for (int i = 0; i < 8; ++i) v[i] = hr[t + i * 256];

  __shared__ float red[8];

  float s = 0.f;
#pragma unroll
  for (int i = 0; i < 8; ++i) s += v[i];
#pragma unroll
  for (int off = 32; off; off >>= 1) s += __shfl_down(s, off);
  if (lane == 0) red[wv] = s;
  __syncthreads();
  const float mu = (red[0] + red[1] + red[2] + red[3]) * (1.f / (float)H);

  float vs = 0.f;
#pragma unroll
  for (int i = 0; i < 8; ++i) {
    float d = v[i] - mu;
    vs += d * d;
  }
#pragma unroll
  for (int off = 32; off; off >>= 1) vs += __shfl_down(vs, off);
  if (lane == 0) red[4 + wv] = vs;
  __syncthreads();
  const float var = (red[4] + red[5] + red[6] + red[7]) * (1.f / (float)H);
  const float rs = rsqrtf(var + LN_EPS);

  __hip_bfloat16* hbr = hb + row * (long)D_DIM;  // row stride 4096 bf16 elems
#pragma unroll
  for (int i = 0; i < 8; ++i) {
    int col = t + i * 256;
    float y = (v[i] - mu) * rs * ln_w[col] + ln_b[col];
    y = fmaxf(y, 0.f);
    hbr[col] = __float2bfloat16(y);
  }
}

// ---------------------------------------------------------------------------
extern "C" void kernel_launch(void* const* d_in, const int* in_sizes, int n_in,
                              void* d_out, int out_size, void* d_ws,
                              size_t ws_size, hipStream_t stream) {
  const float* x = (const float*)d_in[0];     // [8192,4096]
  const float* beta = (const float*)d_in[1];  // [4096,512]
  const float* cmean = (const float*)d_in[2]; // [4096]
  const float* W1 = (const float*)d_in[3];    // [2048,4096]
  const float* b1 = (const float*)d_in[4];    // [2048]
  const float* ln_w = (const float*)d_in[5];  // [2048]
  const float* ln_b = (const float*)d_in[6];  // [2048]
  const float* W2 = (const float*)d_in[7];    // [512,2048]
  const float* b2 = (const float*)d_in[8];    // [512]

  float* out = (float*)d_out;
  float* q0 = out;                                  // [8192,512]
  float* xr = out + (size_t)B_DIM * K_DIM;          // [8192,4096]
  float* q2 = xr + (size_t)B_DIM * D_DIM;           // [8192,512]
  float* q3 = q2 + (size_t)B_DIM * K_DIM;           // [8192,512]

  // ws: h f32 [8192,2048] = 64 MB; LayerNorm overwrites it in place with
  // bf16 h' at row stride 4096 elems. (needs ws_size >= 67108864)
  float* h = (float*)d_ws;
  __hip_bfloat16* hb = (__hip_bfloat16*)d_ws;

  dim3 blk(256, 1, 1);

  // fc1: h = (x - cmean) @ W1^T + b1   [M=8192, N=2048, Kd=4096]
  hipLaunchKernelGGL((gemm_nt<0, float, float>),
                     dim3(H_DIM / 128, B_DIM / 128), blk, 0, stream,
                     x, D_DIM, W1, D_DIM, b1, cmean, h, H_DIM, (float*)nullptr,
                     (float*)nullptr, D_DIM);

  // LayerNorm + ReLU -> bf16 h' (in place)
  hipLaunchKernelGGL(ln_relu_kernel, dim3(B_DIM), blk, 0, stream, d_ws, ln_w,
                     ln_b);

  // fc2: q = h' @ W2^T + b2   [M=8192, N=512, Kd=2048] -> out slots 0,2,3
  hipLaunchKernelGGL((gemm_nt<1, __hip_bfloat16, float>),
                     dim3(K_DIM / 128, B_DIM / 128), blk, 0, stream,
                     hb, D_DIM, W2, H_DIM, b2, (const float*)nullptr, q0, K_DIM,
                     q2, q3, H_DIM);

  // decode: x_recon = sigmoid(q @ beta^T)   [M=8192, N=4096, Kd=512]
  hipLaunchKernelGGL((gemm_nt<2, float, float>),
                     dim3(D_DIM / 128, B_DIM / 128), blk, 0, stream,
                     q0, K_DIM, beta, K_DIM, (const float*)nullptr,
                     (const float*)nullptr, xr, D_DIM, (float*)nullptr,
                     (float*)nullptr, K_DIM);
}

// Round 2
// 644.760 us; speedup vs baseline: 1.3594x; 1.3594x over previous
//
#include <hip/hip_runtime.h>
#include <hip/hip_bf16.h>
#include <cstddef>
#include <cstdint>

#define LN_EPS 1e-5f

// Problem dims (fixed by the reference)
#define B_DIM 8192
#define D_DIM 4096
#define H_DIM 2048
#define K_DIM 512

typedef __bf16 bf16x8_t __attribute__((ext_vector_type(8)));
typedef float f32x4_t __attribute__((ext_vector_type(4)));

// ---------------------------------------------------------------------------
// async global->LDS, 16B per lane. LDS dest = wave-uniform base + lane*16.
// ---------------------------------------------------------------------------
__device__ __forceinline__ void gl2lds16(const __hip_bfloat16* g,
                                         __hip_bfloat16* l) {
  __builtin_amdgcn_global_load_lds(
      (const __attribute__((address_space(1))) uint32_t*)g,
      (__attribute__((address_space(3))) uint32_t*)l, 16, 0, 0);
}

// ---------------------------------------------------------------------------
// f32 -> bf16 pre-convert passes (memory-bound, 8 elems/thread)
// ---------------------------------------------------------------------------
__global__ __launch_bounds__(256) void conv_x_kernel(
    const float* __restrict__ x, const float* __restrict__ cmean,
    __hip_bfloat16* __restrict__ out) {
  const long i = (((long)blockIdx.x << 8) + threadIdx.x) << 3;
  const int col = (int)(i & (D_DIM - 1));
  const float4 a = *(const float4*)(x + i);
  const float4 b = *(const float4*)(x + i + 4);
  const float4 ma = *(const float4*)(cmean + col);
  const float4 mb = *(const float4*)(cmean + col + 4);
  union { __hip_bfloat16 h[8]; uint4 u; } pk;
  pk.h[0] = __float2bfloat16(a.x - ma.x);
  pk.h[1] = __float2bfloat16(a.y - ma.y);
  pk.h[2] = __float2bfloat16(a.z - ma.z);
  pk.h[3] = __float2bfloat16(a.w - ma.w);
  pk.h[4] = __float2bfloat16(b.x - mb.x);
  pk.h[5] = __float2bfloat16(b.y - mb.y);
  pk.h[6] = __float2bfloat16(b.z - mb.z);
  pk.h[7] = __float2bfloat16(b.w - mb.w);
  *(uint4*)(out + i) = pk.u;
}

__global__ __launch_bounds__(256) void conv_w_kernel(
    const float* __restrict__ w, __hip_bfloat16* __restrict__ out) {
  const long i = (((long)blockIdx.x << 8) + threadIdx.x) << 3;
  const float4 a = *(const float4*)(w + i);
  const float4 b = *(const float4*)(w + i + 4);
  union { __hip_bfloat16 h[8]; uint4 u; } pk;
  pk.h[0] = __float2bfloat16(a.x);
  pk.h[1] = __float2bfloat16(a.y);
  pk.h[2] = __float2bfloat16(a.z);
  pk.h[3] = __float2bfloat16(a.w);
  pk.h[4] = __float2bfloat16(b.x);
  pk.h[5] = __float2bfloat16(b.y);
  pk.h[6] = __float2bfloat16(b.z);
  pk.h[7] = __float2bfloat16(b.w);
  *(uint4*)(out + i) = pk.u;
}

// ---------------------------------------------------------------------------
// m97-style NT GEMM: C = A * B^T (+epilogue). A:[M x Kd], B:[N x Kd], both
// bf16 row-major (K-contiguous). 128x128 tile, BK=32, 4 waves 2x2, each wave
// 64x64 as 4x4 mfma_f32_16x16x32_bf16. Staging via global_load_lds width=16:
// LDS tiles are unpadded 128x32 bf16 (row = 4 chunks of 16B, lane-contiguous).
// EPI 0: +bias, store f32 C0                      (fc1 -> h)
// EPI 1: +bias, store f32 C0,C2,C3 + bf16 Cb      (fc2 -> q_logits, q bf16)
// EPI 2: sigmoid, store f32 C0                    (decode -> x_recon)
// ---------------------------------------------------------------------------
template <int EPI>
__global__ __launch_bounds__(256) void gemm_bt(
    const __hip_bfloat16* __restrict__ A, int lda,
    const __hip_bfloat16* __restrict__ Bm, int ldb,
    const float* __restrict__ bias, float* __restrict__ C0, int ldc,
    float* __restrict__ C2, float* __restrict__ C3,
    __hip_bfloat16* __restrict__ Cb, int Kd) {
  __shared__ __hip_bfloat16 lA[128 * 32];
  __shared__ __hip_bfloat16 lB[128 * 32];

  const int t = threadIdx.x;
  const int lane = t & 63;
  const int wv = t >> 6;
  const int wm = (wv >> 1) * 64;  // wave row offset in tile
  const int wn = (wv & 1) * 64;   // wave col offset in tile
  const int fr = lane & 15;       // A-row / B-col within 16, D-col
  const int ko = lane >> 4;       // k-quad

  const long rowA = (long)blockIdx.y * 128;
  const long rowB = (long)blockIdx.x * 128;

  // Staging: 512 chunks of 16B per matrix per K-step. Wave wv covers chunks
  // [wv*128, wv*128+128) in 2 calls of 64. chunk ci -> row ci>>2, col (ci&3)*8.
  const int ci = wv * 128 + lane;
  const __hip_bfloat16* pA0 = A + (rowA + (ci >> 2)) * (long)lda + (ci & 3) * 8;
  const __hip_bfloat16* pA1 = pA0 + 16L * lda;  // ci+64: row+16, same col
  const __hip_bfloat16* pB0 = Bm + (rowB + (ci >> 2)) * (long)ldb + (ci & 3) * 8;
  const __hip_bfloat16* pB1 = pB0 + 16L * ldb;
  __hip_bfloat16* lA0 = lA + wv * 128 * 8;  // wave-uniform LDS bases
  __hip_bfloat16* lA1 = lA0 + 64 * 8;
  __hip_bfloat16* lB0 = lB + wv * 128 * 8;
  __hip_bfloat16* lB1 = lB0 + 64 * 8;

  f32x4_t acc[4][4];
  const f32x4_t zero = {0.f, 0.f, 0.f, 0.f};
#pragma unroll
  for (int mi = 0; mi < 4; ++mi)
#pragma unroll
    for (int ni = 0; ni < 4; ++ni) acc[mi][ni] = zero;

  for (int k0 = 0; k0 < Kd; k0 += 32) {
    gl2lds16(pA0 + k0, lA0);
    gl2lds16(pA1 + k0, lA1);
    gl2lds16(pB0 + k0, lB0);
    gl2lds16(pB1 + k0, lB1);
    __syncthreads();  // drains vmcnt -> LDS tiles complete

    bf16x8_t af[4], bfv[4];
#pragma unroll
    for (int mi = 0; mi < 4; ++mi)
      af[mi] = *(const bf16x8_t*)&lA[(wm + mi * 16 + fr) * 32 + ko * 8];
#pragma unroll
    for (int ni = 0; ni < 4; ++ni)
      bfv[ni] = *(const bf16x8_t*)&lB[(wn + ni * 16 + fr) * 32 + ko * 8];
#pragma unroll
    for (int mi = 0; mi < 4; ++mi)
#pragma unroll
      for (int ni = 0; ni < 4; ++ni)
        acc[mi][ni] = __builtin_amdgcn_mfma_f32_16x16x32_bf16(
            af[mi], bfv[ni], acc[mi][ni], 0, 0, 0);
    __syncthreads();  // all reads done before next iter's staging
  }

  // Epilogue. C/D layout (verified m89/m91): col = lane&15, row = (lane>>4)*4+reg
  const long cRow0 = rowA + wm;
  const int cCol0 = (int)rowB + wn;
#pragma unroll
  for (int mi = 0; mi < 4; ++mi) {
#pragma unroll
    for (int ni = 0; ni < 4; ++ni) {
      f32x4_t a = acc[mi][ni];
      int col = cCol0 + ni * 16 + fr;
#pragma unroll
      for (int r = 0; r < 4; ++r) {
        long row = cRow0 + mi * 16 + ko * 4 + r;
        float val = a[r];
        if constexpr (EPI == 0) {
          val += bias[col];
          C0[row * (long)ldc + col] = val;
        } else if constexpr (EPI == 1) {
          val += bias[col];
          C0[row * (long)ldc + col] = val;
          C2[row * (long)ldc + col] = val;
          C3[row * (long)ldc + col] = val;
          Cb[row * (long)ldc + col] = __float2bfloat16(val);
        } else {
          val = 1.f / (1.f + __expf(-val));
          C0[row * (long)ldc + col] = val;
        }
      }
    }
  }
}

// ---------------------------------------------------------------------------
// Row LayerNorm + ReLU over h [8192 x 2048] f32; writes bf16 h' IN PLACE
// (bf16 row stride 4096 elems = the f32 row byte size). Reads before writes.
// ---------------------------------------------------------------------------
__global__ __launch_bounds__(256) void ln_relu_kernel(
    void* hptr, const float* __restrict__ ln_w, const float* __restrict__ ln_b) {
  const int H = H_DIM;
  float* h = (float*)hptr;
  __hip_bfloat16* hb = (__hip_bfloat16*)hptr;

  const long row = blockIdx.x;
  const int t = threadIdx.x;
  const int lane = t & 63;
  const int wv = t >> 6;
  const float* hr = h + row * H;

  float v[8];
#pragma unroll
  for (int i = 0; i < 8; ++i) v[i] = hr[t + i * 256];

  __shared__ float red[8];

  float s = 0.f;
#pragma unroll
  for (int i = 0; i < 8; ++i) s += v[i];
#pragma unroll
  for (int off = 32; off; off >>= 1) s += __shfl_down(s, off);
  if (lane == 0) red[wv] = s;
  __syncthreads();
  const float mu = (red[0] + red[1] + red[2] + red[3]) * (1.f / (float)H);

  float vs = 0.f;
#pragma unroll
  for (int i = 0; i < 8; ++i) {
    float d = v[i] - mu;
    vs += d * d;
  }
#pragma unroll
  for (int off = 32; off; off >>= 1) vs += __shfl_down(vs, off);
  if (lane == 0) red[4 + wv] = vs;
  __syncthreads();
  const float var = (red[4] + red[5] + red[6] + red[7]) * (1.f / (float)H);
  const float rs = rsqrtf(var + LN_EPS);

  __hip_bfloat16* hbr = hb + row * (long)D_DIM;  // stride 4096 bf16 elems
#pragma unroll
  for (int i = 0; i < 8; ++i) {
    int col = t + i * 256;
    float y = (v[i] - mu) * rs * ln_w[col] + ln_b[col];
    y = fmaxf(y, 0.f);
    hbr[col] = __float2bfloat16(y);
  }
}

// ---------------------------------------------------------------------------
extern "C" void kernel_launch(void* const* d_in, const int* in_sizes, int n_in,
                              void* d_out, int out_size, void* d_ws,
                              size_t ws_size, hipStream_t stream) {
  const float* x = (const float*)d_in[0];     // [8192,4096]
  const float* beta = (const float*)d_in[1];  // [4096,512]
  // d_in[2] = compound_mean [4096]
  const float* cmean = (const float*)d_in[2];
  const float* W1 = (const float*)d_in[3];    // [2048,4096]
  const float* b1 = (const float*)d_in[4];    // [2048]
  const float* ln_w = (const float*)d_in[5];  // [2048]
  const float* ln_b = (const float*)d_in[6];  // [2048]
  const float* W2 = (const float*)d_in[7];    // [512,2048]
  const float* b2 = (const float*)d_in[8];    // [512]

  float* out = (float*)d_out;
  float* q0 = out;                          // [8192,512]
  float* xr = out + (size_t)B_DIM * K_DIM;  // [8192,4096] — 134 MB region
  float* q2 = xr + (size_t)B_DIM * D_DIM;   // [8192,512]
  float* q3 = q2 + (size_t)B_DIM * K_DIM;   // [8192,512]

  // Scratch inside d_out's xr region (dead until final decode GEMM):
  //   xb: bf16(x - cmean) [8192,4096] = 64 MB at xr+0
  //   h : f32 fc1 output  [8192,2048] = 64 MB at xr + 16.78M floats
  // (64+64 = exactly the 134.2 MB xr region). Decode overwrites both — dead.
  __hip_bfloat16* xb = (__hip_bfloat16*)xr;
  float* h = xr + (size_t)B_DIM * D_DIM / 2;
  __hip_bfloat16* hb = (__hip_bfloat16*)h;  // ln_relu writes bf16 in place

  // ws: bf16 weights + q bf16 (30 MB total; ws proven >= 64 MB)
  __hip_bfloat16* W1b = (__hip_bfloat16*)d_ws;        // 2048*4096
  __hip_bfloat16* W2b = W1b + (size_t)H_DIM * D_DIM;  // 512*2048
  __hip_bfloat16* betab = W2b + (size_t)K_DIM * H_DIM;  // 4096*512
  __hip_bfloat16* qb = betab + (size_t)D_DIM * K_DIM;   // 8192*512

  dim3 blk(256, 1, 1);

  // Pre-convert to bf16 (memory-bound)
  hipLaunchKernelGGL(conv_x_kernel, dim3((B_DIM * (size_t)D_DIM) / 2048), blk,
                     0, stream, x, cmean, xb);
  hipLaunchKernelGGL(conv_w_kernel, dim3((H_DIM * (size_t)D_DIM) / 2048), blk,
                     0, stream, W1, W1b);
  hipLaunchKernelGGL(conv_w_kernel, dim3((K_DIM * (size_t)H_DIM) / 2048), blk,
                     0, stream, W2, W2b);
  hipLaunchKernelGGL(conv_w_kernel, dim3((D_DIM * (size_t)K_DIM) / 2048), blk,
                     0, stream, beta, betab);

  // fc1: h = xb @ W1b^T + b1   [M=8192, N=2048, Kd=4096]
  hipLaunchKernelGGL((gemm_bt<0>), dim3(H_DIM / 128, B_DIM / 128), blk, 0,
                     stream, xb, D_DIM, W1b, D_DIM, b1, h, H_DIM,
                     (float*)nullptr, (float*)nullptr,
                     (__hip_bfloat16*)nullptr, D_DIM);

  // LayerNorm + ReLU -> bf16 h' in place (row stride 4096)
  hipLaunchKernelGGL(ln_relu_kernel, dim3(B_DIM), blk, 0, stream, (void*)h,
                     ln_w, ln_b);

  // fc2: q = h' @ W2b^T + b2   [M=8192, N=512, Kd=2048] -> q0,q2,q3 + qb bf16
  hipLaunchKernelGGL((gemm_bt<1>), dim3(K_DIM / 128, B_DIM / 128), blk, 0,
                     stream, hb, D_DIM, W2b, H_DIM, b2, q0, K_DIM, q2, q3, qb,
                     H_DIM);

  // decode: x_recon = sigmoid(qb @ betab^T)  [M=8192, N=4096, Kd=512]
  // (overwrites xb and h — both dead by now)
  hipLaunchKernelGGL((gemm_bt<2>), dim3(D_DIM / 128, B_DIM / 128), blk, 0,
                     stream, qb, K_DIM, betab, K_DIM, (const float*)nullptr,
                     xr, D_DIM, (float*)nullptr, (float*)nullptr,
                     (__hip_bfloat16*)nullptr, K_DIM);
}

// Round 3
// 635.390 us; speedup vs baseline: 1.3795x; 1.0147x over previous
//
#include <hip/hip_runtime.h>
#include <hip/hip_bf16.h>
#include <cstddef>
#include <cstdint>

#define LN_EPS 1e-5f

// Problem dims (fixed by the reference)
#define B_DIM 8192
#define D_DIM 4096
#define H_DIM 2048
#define K_DIM 512

typedef __bf16 bf16x8_t __attribute__((ext_vector_type(8)));
typedef float f32x4_t __attribute__((ext_vector_type(4)));

// ---------------------------------------------------------------------------
// async global->LDS, 16B per lane. LDS dest = wave-uniform base + lane*16.
// ---------------------------------------------------------------------------
__device__ __forceinline__ void gl2lds16(const __hip_bfloat16* g,
                                         __hip_bfloat16* l) {
  __builtin_amdgcn_global_load_lds(
      (const __attribute__((address_space(1))) uint32_t*)g,
      (__attribute__((address_space(3))) uint32_t*)l, 16, 0, 0);
}

// ---------------------------------------------------------------------------
// f32 -> bf16 pre-convert passes (memory-bound, 8 elems/thread)
// ---------------------------------------------------------------------------
__global__ __launch_bounds__(256) void conv_x_kernel(
    const float* __restrict__ x, const float* __restrict__ cmean,
    __hip_bfloat16* __restrict__ out) {
  const long i = (((long)blockIdx.x << 8) + threadIdx.x) << 3;
  const int col = (int)(i & (D_DIM - 1));
  const float4 a = *(const float4*)(x + i);
  const float4 b = *(const float4*)(x + i + 4);
  const float4 ma = *(const float4*)(cmean + col);
  const float4 mb = *(const float4*)(cmean + col + 4);
  union { __hip_bfloat16 h[8]; uint4 u; } pk;
  pk.h[0] = __float2bfloat16(a.x - ma.x);
  pk.h[1] = __float2bfloat16(a.y - ma.y);
  pk.h[2] = __float2bfloat16(a.z - ma.z);
  pk.h[3] = __float2bfloat16(a.w - ma.w);
  pk.h[4] = __float2bfloat16(b.x - mb.x);
  pk.h[5] = __float2bfloat16(b.y - mb.y);
  pk.h[6] = __float2bfloat16(b.z - mb.z);
  pk.h[7] = __float2bfloat16(b.w - mb.w);
  *(uint4*)(out + i) = pk.u;
}

// One launch converting W1 (4096 blocks), W2 (512), beta (1024). 2048 f32/blk.
__global__ __launch_bounds__(256) void conv_w3_kernel(
    const float* __restrict__ W1, const float* __restrict__ W2,
    const float* __restrict__ beta, __hip_bfloat16* __restrict__ W1b,
    __hip_bfloat16* __restrict__ W2b, __hip_bfloat16* __restrict__ betab) {
  const int blk = blockIdx.x;
  const float* src;
  __hip_bfloat16* dst;
  long base;
  if (blk < 4096) {
    src = W1; dst = W1b; base = blk;
  } else if (blk < 4608) {
    src = W2; dst = W2b; base = blk - 4096;
  } else {
    src = beta; dst = betab; base = blk - 4608;
  }
  const long i = ((base << 8) + threadIdx.x) << 3;
  const float4 a = *(const float4*)(src + i);
  const float4 b = *(const float4*)(src + i + 4);
  union { __hip_bfloat16 h[8]; uint4 u; } pk;
  pk.h[0] = __float2bfloat16(a.x);
  pk.h[1] = __float2bfloat16(a.y);
  pk.h[2] = __float2bfloat16(a.z);
  pk.h[3] = __float2bfloat16(a.w);
  pk.h[4] = __float2bfloat16(b.x);
  pk.h[5] = __float2bfloat16(b.y);
  pk.h[6] = __float2bfloat16(b.z);
  pk.h[7] = __float2bfloat16(b.w);
  *(uint4*)(dst + i) = pk.u;
}

// ---------------------------------------------------------------------------
// m97-style NT GEMM: C = A * B^T (+epilogue). A:[M x Kd], B:[N x Kd], both
// bf16 row-major (K-contiguous). 128x128 tile, BK=32, 4 waves 2x2, each wave
// 64x64 as 4x4 mfma_f32_16x16x32_bf16. Staging via global_load_lds width=16.
//
// LDS bank-conflict swizzle: logical chunk (row, kq) [kq = 8-elem K-group]
// lives at physical chunk row*4 + (kq ^ ((row>>1)&3)). global_load_lds can't
// scatter, so the swizzle is inverted in the STAGING SOURCE index (compile-
// time XOR; invariant under the +64-chunk second call since bit6 of the chunk
// id doesn't touch bits 0..2). Fragment reads fold it into a per-lane
// constant: bits 1..2 of the fragment row come only from fr (wm is bit6,
// mi*16 bits 4..5), so kos = ko ^ ((fr>>1)&3). Any 8 contiguous lanes then
// cover all 8 four-bank groups -> conflict-free ds_read_b128.
//
// EPI 0: +bias, store f32 C0                      (fc1 -> h)
// EPI 1: +bias, store f32 C0,C2,C3 + bf16 Cb      (fc2 -> q_logits, q bf16)
// EPI 2: sigmoid, store f32 C0                    (decode -> x_recon)
// ---------------------------------------------------------------------------
template <int EPI>
__global__ __launch_bounds__(256) void gemm_bt(
    const __hip_bfloat16* __restrict__ A, int lda,
    const __hip_bfloat16* __restrict__ Bm, int ldb,
    const float* __restrict__ bias, float* __restrict__ C0, int ldc,
    float* __restrict__ C2, float* __restrict__ C3,
    __hip_bfloat16* __restrict__ Cb, int Kd) {
  __shared__ __hip_bfloat16 lA[128 * 32];
  __shared__ __hip_bfloat16 lB[128 * 32];

  const int t = threadIdx.x;
  const int lane = t & 63;
  const int wv = t >> 6;
  const int wm = (wv >> 1) * 64;  // wave row offset in tile
  const int wn = (wv & 1) * 64;   // wave col offset in tile
  const int fr = lane & 15;       // A-row / B-col within 16, D-col
  const int ko = lane >> 4;       // k-quad
  const int kos = (ko ^ ((fr >> 1) & 3)) * 8;  // swizzled k-offset (elems)

  const long rowA = (long)blockIdx.y * 128;
  const long rowB = (long)blockIdx.x * 128;

  // Staging: 512 chunks of 16B per matrix per K-step; wave wv fills LDS slots
  // [wv*128, wv*128+128) in 2 calls of 64. Physical slot ci -> logical
  // row = ci>>2, kq = (ci&3) ^ ((ci>>3)&3)  (swizzle inverse).
  const int ci = wv * 128 + lane;
  const int srow = ci >> 2;
  const int scol = (((ci & 3) ^ ((ci >> 3) & 3))) * 8;
  const __hip_bfloat16* pA0 = A + (rowA + srow) * (long)lda + scol;
  const __hip_bfloat16* pA1 = pA0 + 16L * lda;  // slot ci+64: row+16, same kq
  const __hip_bfloat16* pB0 = Bm + (rowB + srow) * (long)ldb + scol;
  const __hip_bfloat16* pB1 = pB0 + 16L * ldb;
  __hip_bfloat16* lA0 = lA + wv * 128 * 8;  // wave-uniform LDS bases
  __hip_bfloat16* lA1 = lA0 + 64 * 8;
  __hip_bfloat16* lB0 = lB + wv * 128 * 8;
  __hip_bfloat16* lB1 = lB0 + 64 * 8;

  f32x4_t acc[4][4];
  const f32x4_t zero = {0.f, 0.f, 0.f, 0.f};
#pragma unroll
  for (int mi = 0; mi < 4; ++mi)
#pragma unroll
    for (int ni = 0; ni < 4; ++ni) acc[mi][ni] = zero;

  for (int k0 = 0; k0 < Kd; k0 += 32) {
    gl2lds16(pA0 + k0, lA0);
    gl2lds16(pA1 + k0, lA1);
    gl2lds16(pB0 + k0, lB0);
    gl2lds16(pB1 + k0, lB1);
    __syncthreads();  // drains vmcnt -> LDS tiles complete

    bf16x8_t af[4], bfv[4];
#pragma unroll
    for (int mi = 0; mi < 4; ++mi)
      af[mi] = *(const bf16x8_t*)&lA[(wm + mi * 16 + fr) * 32 + kos];
#pragma unroll
    for (int ni = 0; ni < 4; ++ni)
      bfv[ni] = *(const bf16x8_t*)&lB[(wn + ni * 16 + fr) * 32 + kos];
#pragma unroll
    for (int mi = 0; mi < 4; ++mi)
#pragma unroll
      for (int ni = 0; ni < 4; ++ni)
        acc[mi][ni] = __builtin_amdgcn_mfma_f32_16x16x32_bf16(
            af[mi], bfv[ni], acc[mi][ni], 0, 0, 0);
    __syncthreads();  // all reads done before next iter's staging
  }

  // Epilogue. C/D layout (verified m89/m91): col = lane&15, row = (lane>>4)*4+reg
  const long cRow0 = rowA + wm;
  const int cCol0 = (int)rowB + wn;
#pragma unroll
  for (int mi = 0; mi < 4; ++mi) {
#pragma unroll
    for (int ni = 0; ni < 4; ++ni) {
      f32x4_t a = acc[mi][ni];
      int col = cCol0 + ni * 16 + fr;
#pragma unroll
      for (int r = 0; r < 4; ++r) {
        long row = cRow0 + mi * 16 + ko * 4 + r;
        float val = a[r];
        if constexpr (EPI == 0) {
          val += bias[col];
          C0[row * (long)ldc + col] = val;
        } else if constexpr (EPI == 1) {
          val += bias[col];
          C0[row * (long)ldc + col] = val;
          C2[row * (long)ldc + col] = val;
          C3[row * (long)ldc + col] = val;
          Cb[row * (long)ldc + col] = __float2bfloat16(val);
        } else {
          val = 1.f / (1.f + __expf(-val));
          C0[row * (long)ldc + col] = val;
        }
      }
    }
  }
}

// ---------------------------------------------------------------------------
// Row LayerNorm + ReLU over h [8192 x 2048] f32; writes bf16 h' IN PLACE
// (bf16 row stride 4096 elems = the f32 row byte size). Reads before writes.
// ---------------------------------------------------------------------------
__global__ __launch_bounds__(256) void ln_relu_kernel(
    void* hptr, const float* __restrict__ ln_w, const float* __restrict__ ln_b) {
  const int H = H_DIM;
  float* h = (float*)hptr;
  __hip_bfloat16* hb = (__hip_bfloat16*)hptr;

  const long row = blockIdx.x;
  const int t = threadIdx.x;
  const int lane = t & 63;
  const int wv = t >> 6;
  const float* hr = h + row * H;

  float v[8];
#pragma unroll
  for (int i = 0; i < 8; ++i) v[i] = hr[t + i * 256];

  __shared__ float red[8];

  float s = 0.f;
#pragma unroll
  for (int i = 0; i < 8; ++i) s += v[i];
#pragma unroll
  for (int off = 32; off; off >>= 1) s += __shfl_down(s, off);
  if (lane == 0) red[wv] = s;
  __syncthreads();
  const float mu = (red[0] + red[1] + red[2] + red[3]) * (1.f / (float)H);

  float vs = 0.f;
#pragma unroll
  for (int i = 0; i < 8; ++i) {
    float d = v[i] - mu;
    vs += d * d;
  }
#pragma unroll
  for (int off = 32; off; off >>= 1) vs += __shfl_down(vs, off);
  if (lane == 0) red[4 + wv] = vs;
  __syncthreads();
  const float var = (red[4] + red[5] + red[6] + red[7]) * (1.f / (float)H);
  const float rs = rsqrtf(var + LN_EPS);

  __hip_bfloat16* hbr = hb + row * (long)D_DIM;  // stride 4096 bf16 elems
#pragma unroll
  for (int i = 0; i < 8; ++i) {
    int col = t + i * 256;
    float y = (v[i] - mu) * rs * ln_w[col] + ln_b[col];
    y = fmaxf(y, 0.f);
    hbr[col] = __float2bfloat16(y);
  }
}

// ---------------------------------------------------------------------------
extern "C" void kernel_launch(void* const* d_in, const int* in_sizes, int n_in,
                              void* d_out, int out_size, void* d_ws,
                              size_t ws_size, hipStream_t stream) {
  const float* x = (const float*)d_in[0];     // [8192,4096]
  const float* beta = (const float*)d_in[1];  // [4096,512]
  const float* cmean = (const float*)d_in[2]; // [4096]
  const float* W1 = (const float*)d_in[3];    // [2048,4096]
  const float* b1 = (const float*)d_in[4];    // [2048]
  const float* ln_w = (const float*)d_in[5];  // [2048]
  const float* ln_b = (const float*)d_in[6];  // [2048]
  const float* W2 = (const float*)d_in[7];    // [512,2048]
  const float* b2 = (const float*)d_in[8];    // [512]

  float* out = (float*)d_out;
  float* q0 = out;                          // [8192,512]
  float* xr = out + (size_t)B_DIM * K_DIM;  // [8192,4096] — 134 MB region
  float* q2 = xr + (size_t)B_DIM * D_DIM;   // [8192,512]
  float* q3 = q2 + (size_t)B_DIM * K_DIM;   // [8192,512]

  // Scratch inside d_out's xr region (dead until final decode GEMM):
  //   xb: bf16(x - cmean) [8192,4096] = 64 MB at xr+0
  //   h : f32 fc1 output  [8192,2048] = 64 MB at xr + 16.78M floats
  __hip_bfloat16* xb = (__hip_bfloat16*)xr;
  float* h = xr + (size_t)B_DIM * D_DIM / 2;
  __hip_bfloat16* hb = (__hip_bfloat16*)h;  // ln_relu writes bf16 in place

  // ws: bf16 weights + q bf16 (30 MB total; ws proven >= 64 MB)
  __hip_bfloat16* W1b = (__hip_bfloat16*)d_ws;          // 2048*4096
  __hip_bfloat16* W2b = W1b + (size_t)H_DIM * D_DIM;    // 512*2048
  __hip_bfloat16* betab = W2b + (size_t)K_DIM * H_DIM;  // 4096*512
  __hip_bfloat16* qb = betab + (size_t)D_DIM * K_DIM;   // 8192*512

  dim3 blk(256, 1, 1);

  // Pre-convert to bf16 (memory-bound, 2 launches)
  hipLaunchKernelGGL(conv_x_kernel, dim3((B_DIM * (size_t)D_DIM) / 2048), blk,
                     0, stream, x, cmean, xb);
  hipLaunchKernelGGL(conv_w3_kernel, dim3(4096 + 512 + 1024), blk, 0, stream,
                     W1, W2, beta, W1b, W2b, betab);

  // fc1: h = xb @ W1b^T + b1   [M=8192, N=2048, Kd=4096]
  hipLaunchKernelGGL((gemm_bt<0>), dim3(H_DIM / 128, B_DIM / 128), blk, 0,
                     stream, xb, D_DIM, W1b, D_DIM, b1, h, H_DIM,
                     (float*)nullptr, (float*)nullptr,
                     (__hip_bfloat16*)nullptr, D_DIM);

  // LayerNorm + ReLU -> bf16 h' in place (row stride 4096)
  hipLaunchKernelGGL(ln_relu_kernel, dim3(B_DIM), blk, 0, stream, (void*)h,
                     ln_w, ln_b);

  // fc2: q = h' @ W2b^T + b2   [M=8192, N=512, Kd=2048] -> q0,q2,q3 + qb bf16
  hipLaunchKernelGGL((gemm_bt<1>), dim3(K_DIM / 128, B_DIM / 128), blk, 0,
                     stream, hb, D_DIM, W2b, H_DIM, b2, q0, K_DIM, q2, q3, qb,
                     H_DIM);

  // decode: x_recon = sigmoid(qb @ betab^T)  [M=8192, N=4096, Kd=512]
  hipLaunchKernelGGL((gemm_bt<2>), dim3(D_DIM / 128, B_DIM / 128), blk, 0,
                     stream, qb, K_DIM, betab, K_DIM, (const float*)nullptr,
                     xr, D_DIM, (float*)nullptr, (float*)nullptr,
                     (__hip_bfloat16*)nullptr, K_DIM);
}